// Round 7
// baseline (55.276 us; speedup 1.0000x reference)
//
#include <hip/hip_runtime.h>
#include <stdint.h>

// y[b,r] = sum_t x[b, idx[r,t]] * w[r,t] - bias[r]
// fp32 x (1024x4096), fp32 w (8192x32), fp32 bias (8192), int32 idx (8192x32), fp32 out (1024x8192)
//
// LDS-gather design (r6: 220->50us): x pre-transposed to bf16 8-batch slices
// (64 KB); block stages slice in LDS, serves all gathers via ds_read_b64.
// r7: 1024-thread blocks -> 8 waves/SIMD (was 4) to hide L2+LDS latency;
// idx/w fused into one uint2 stream (halves stream-load instructions).

#define IN_DIM   4096
#define OUT_DIM  8192
#define BATCH    1024
#define NACT     32

#define B_SLICE      8                        // batches per LDS slice
#define N_SLICE      (BATCH / B_SLICE)        // 128
#define SLICE_WORDS  (IN_DIM * (B_SLICE / 2)) // 16384 words = 64 KB
#define R_PER_BLK    2048
#define N_RSPLIT     (OUT_DIM / R_PER_BLK)    // 4
#define MAIN_THREADS 1024

__device__ __forceinline__ ushort f2bf(float f) {
    union { float f; uint32_t i; } v; v.f = f;
    uint32_t b = v.i + 0x7fffu + ((v.i >> 16) & 1u);   // RNE
    return (ushort)(b >> 16);
}
__device__ __forceinline__ float blo(uint32_t v) {
    union { uint32_t i; float f; } u; u.i = v << 16; return u.f;
}
__device__ __forceinline__ float bhi(uint32_t v) {
    union { uint32_t i; float f; } u; u.i = v & 0xffff0000u; return u.f;
}
__device__ __forceinline__ float asf(uint32_t v) {
    union { uint32_t i; float f; } u; u.i = v; return u.f;
}

// ---- x (1024x4096 fp32) -> xTs [slice=b/8][c][bp=(b%8)/2] bf16-pair words ----
__global__ __launch_bounds__(256) void x_to_sliced_bf16(const float* __restrict__ x,
                                                        uint32_t* __restrict__ xTs) {
    __shared__ float tile[64][65];
    const int tid = threadIdx.x;
    const int c0 = blockIdx.x * 64, b0 = blockIdx.y * 64;
    const int tx = tid & 63, ty0 = tid >> 6;
#pragma unroll
    for (int k = 0; k < 16; ++k) {
        int b = ty0 + k * 4;
        tile[b][tx] = x[(size_t)(b0 + b) * IN_DIM + c0 + tx];
    }
    __syncthreads();
#pragma unroll
    for (int k = 0; k < 8; ++k) {
        int lin = k * 256 + tid;            // 0..2047 = 8 sl x 64 c x 4 bp
        int bp = lin & 3;
        int c  = (lin >> 2) & 63;
        int sl = lin >> 8;
        ushort u0 = f2bf(tile[sl * 8 + 2 * bp    ][c]);
        ushort u1 = f2bf(tile[sl * 8 + 2 * bp + 1][c]);
        xTs[(size_t)((b0 >> 3) + sl) * SLICE_WORDS + (size_t)(c0 + c) * 4 + bp] =
            u0 | ((uint32_t)u1 << 16);
    }
}

// ---- idx/w (8192x32 row-major) -> fused iwT[t][r] = (idx, w bits) uint2 ----
__global__ __launch_bounds__(256) void iw_transpose(const int* __restrict__ idx,
                                                    const float* __restrict__ w,
                                                    uint2* __restrict__ iwT) {
    __shared__ int   si[64][33];
    __shared__ float sw[64][33];
    const int tid = threadIdx.x;
    const int r0 = blockIdx.x * 64;
    const uint32_t* gi = (const uint32_t*)idx;
    const bool idx64 = ((gi[1] | gi[3] | gi[5] | gi[7] | gi[9] | gi[11] | gi[13] | gi[15]) == 0u);
#pragma unroll
    for (int k = 0; k < 8; ++k) {
        int lin = k * 256 + tid;            // 2048 = 64 rows x 32 t
        int row = lin >> 5, t = lin & 31;
        int v;
        if (!idx64) v = idx[(size_t)(r0 + row) * NACT + t];
        else        v = idx[((size_t)(r0 + row) * NACT + t) * 2];
        si[row][t] = v;
        sw[row][t] = w[(size_t)(r0 + row) * NACT + t];
    }
    __syncthreads();
#pragma unroll
    for (int k = 0; k < 8; ++k) {
        int lin = k * 256 + tid;
        int t = lin >> 6, row = lin & 63;
        uint2 q;
        q.x = (uint32_t)si[row][t];
        union { float f; uint32_t i; } u; u.f = sw[row][t];
        q.y = u.i;
        iwT[(size_t)t * OUT_DIM + r0 + row] = q;   // 512B/wave coalesced
    }
}

// ---- main: block = 8-batch slice (64 KB LDS) x 2048 rows; gathers via LDS ----
__global__ __launch_bounds__(MAIN_THREADS, 8) void lds_gather(const uint32_t* __restrict__ xTs,
                                                              const uint2* __restrict__ iwT,
                                                              const float* __restrict__ bias,
                                                              float* __restrict__ out) {
    __shared__ uint32_t s_x[SLICE_WORDS];   // 64 KB -> 2 blocks/CU, 32 waves/CU
    const int tid = threadIdx.x;
    const int slice  = blockIdx.x & (N_SLICE - 1);
    const int rsplit = blockIdx.x >> 7;
    const int b0  = slice * B_SLICE;
    const int r0g = rsplit * R_PER_BLK;

    { // stage the 64 KB slice: linear, conflict-free ds_write_b128
        const uint4* g = (const uint4*)(xTs + (size_t)slice * SLICE_WORDS);
        uint4* s = (uint4*)s_x;
#pragma unroll
        for (int it = 0; it < 4; ++it) s[it * MAIN_THREADS + tid] = g[it * MAIN_THREADS + tid];
    }
    __syncthreads();

    const int wv = tid >> 6, lane = tid & 63;     // wv in [0,16)
    const int rsub = lane >> 1, wl = lane & 1;    // wave = 32 rows x 2 half-slices
    const uint32_t loff = (uint32_t)wl * 8u;

#pragma unroll 1
    for (int rg = 0; rg < 4; ++rg) {
        const int r = r0g + (wv * 4 + rg) * 32 + rsub;
        float a0 = 0.f, a1 = 0.f, a2 = 0.f, a3 = 0.f;
        const uint2* ip = iwT + r;
#pragma unroll 8
        for (int t = 0; t < NACT; ++t) {
            const uint2 q = ip[(size_t)t * OUT_DIM];   // idx+w fused, 512B/wave
            const float wg = asf(q.y);
            uint2 v = *(const uint2*)((const char*)s_x + (q.x << 4) + loff);
            a0 = fmaf(blo(v.x), wg, a0);
            a1 = fmaf(bhi(v.x), wg, a1);
            a2 = fmaf(blo(v.y), wg, a2);
            a3 = fmaf(bhi(v.y), wg, a3);
        }
        const float bv = bias[r];
        const size_t ob = (size_t)(b0 + wl * 4) * OUT_DIM + r;
        out[ob              ] = a0 - bv;   // 2x128B full-line segments per instr
        out[ob +     OUT_DIM] = a1 - bv;
        out[ob + 2 * OUT_DIM] = a2 - bv;
        out[ob + 3 * OUT_DIM] = a3 - bv;
    }
}

// ---- insurance fallback (ws too small): one thread per output ----
__global__ __launch_bounds__(256) void direct_gather(const float* __restrict__ x,
                                                     const int* __restrict__ idx,
                                                     const float* __restrict__ w,
                                                     const float* __restrict__ bias,
                                                     float* __restrict__ out) {
    const uint32_t* gi = (const uint32_t*)idx;
    const bool idx64 = ((gi[1] | gi[3] | gi[5] | gi[7] | gi[9] | gi[11] | gi[13] | gi[15]) == 0u);
    int o = blockIdx.x * 256 + threadIdx.x;
    int b = o >> 13, r = o & (OUT_DIM - 1);
    float acc = 0.f;
    const float* xb = x + (size_t)b * IN_DIM;
    for (int t = 0; t < NACT; ++t) {
        int c = idx64 ? idx[((size_t)r * NACT + t) * 2] : idx[(size_t)r * NACT + t];
        acc = fmaf(xb[c], w[(size_t)r * NACT + t], acc);
    }
    out[(size_t)b * OUT_DIM + r] = acc - bias[r];
}

extern "C" void kernel_launch(void* const* d_in, const int* in_sizes, int n_in,
                              void* d_out, int out_size, void* d_ws, size_t ws_size,
                              hipStream_t stream) {
    const float* x    = (const float*)d_in[0];
    const float* wk   = (const float*)d_in[1];
    const float* bias = (const float*)d_in[2];
    const int*   idx  = (const int*)d_in[3];
    float*       out  = (float*)d_out;

    const size_t xTs_bytes = (size_t)N_SLICE * SLICE_WORDS * 4;   // 8 MB
    const size_t iwT_bytes = (size_t)NACT * OUT_DIM * 8;          // 2 MB
    const size_t need = xTs_bytes + iwT_bytes;                    // 10 MB

    if (ws_size >= need) {
        uint32_t* xTs = (uint32_t*)d_ws;
        uint2*    iwT = (uint2*)((char*)d_ws + xTs_bytes);
        x_to_sliced_bf16<<<dim3(IN_DIM / 64, BATCH / 64), 256, 0, stream>>>(x, xTs);
        iw_transpose<<<OUT_DIM / 64, 256, 0, stream>>>(idx, wk, iwT);
        lds_gather<<<N_SLICE * N_RSPLIT, MAIN_THREADS, 0, stream>>>(xTs, iwT, bias, out);
    } else {
        direct_gather<<<(BATCH * OUT_DIM) / 256, 256, 0, stream>>>(x, idx, wk, bias, out);
    }
}

// Round 8
// 39.649 us; speedup vs baseline: 1.3941x; 1.3941x over previous
//
#include <hip/hip_runtime.h>
#include <stdint.h>

// y[b,r] = sum_t x[b, idx[r,t]] * w[r,t] - bias[r]
// fp32 x (1024x4096), fp32 w (8192x32), fp32 bias (8192), int idx (8192x32), fp32 out
//
// r8: LDS-gather, 32KB slices (4 batches) for 4 blocks/CU co-residency (r7 showed
// 64KB blocks cap at 50% occupancy); x-staging fused into main kernel; idx+w
// packed into one u32 (addr<<3 | bf16w<<16) halving the L2 stream.

#define IN_DIM   4096
#define OUT_DIM  8192
#define BATCH    1024
#define NACT     32

#define B_SLICE      4                         // batches per LDS slice
#define N_SLICE      (BATCH / B_SLICE)         // 256
#define SLICE_WORDS  (IN_DIM * 2)              // 8192 u32 = 32 KB
#define R_PER_BLK    2048
#define N_RSPLIT     (OUT_DIM / R_PER_BLK)     // 4
#define MAIN_THREADS 512

__device__ __forceinline__ ushort f2bf(float f) {
    union { float f; uint32_t i; } v; v.f = f;
    uint32_t b = v.i + 0x7fffu + ((v.i >> 16) & 1u);   // RNE
    return (ushort)(b >> 16);
}
__device__ __forceinline__ float blo(uint32_t v) {
    union { uint32_t i; float f; } u; u.i = v << 16; return u.f;
}
__device__ __forceinline__ float bhi(uint32_t v) {
    union { uint32_t i; float f; } u; u.i = v & 0xffff0000u; return u.f;
}
__device__ __forceinline__ float asf(uint32_t v) {
    union { uint32_t i; float f; } u; u.i = v; return u.f;
}

// ---- idx/w (8192x32 row-major) -> iwPk[t][r] = (c<<3) | (bf16(w)<<16) ----
// c < 4096 -> c<<3 fits 15 bits; bf16 w in [31:16]; unpack = 1 v_and each.
__global__ __launch_bounds__(256) void iw_pack(const int* __restrict__ idx,
                                               const float* __restrict__ w,
                                               uint32_t* __restrict__ iwPk) {
    __shared__ uint32_t sq[64][33];
    const int tid = threadIdx.x;
    const int r0 = blockIdx.x * 64;
    const uint32_t* gi = (const uint32_t*)idx;
    const bool idx64 = ((gi[1] | gi[3] | gi[5] | gi[7] | gi[9] | gi[11] | gi[13] | gi[15]) == 0u);
#pragma unroll
    for (int k = 0; k < 8; ++k) {
        int lin = k * 256 + tid;            // 2048 = 64 rows x 32 t
        int row = lin >> 5, t = lin & 31;
        int c;
        if (!idx64) c = idx[(size_t)(r0 + row) * NACT + t];
        else        c = idx[((size_t)(r0 + row) * NACT + t) * 2];
        float wv = w[(size_t)(r0 + row) * NACT + t];
        sq[row][t] = ((uint32_t)c << 3) | ((uint32_t)f2bf(wv) << 16);
    }
    __syncthreads();
#pragma unroll
    for (int k = 0; k < 8; ++k) {
        int lin = k * 256 + tid;
        int t = lin >> 6, row = lin & 63;
        iwPk[(size_t)t * OUT_DIM + r0 + row] = sq[row][t];   // 256B/wave coalesced
    }
}

// ---- main: block = 4-batch slice (32 KB LDS) x 2048 rows; gathers via LDS ----
__global__ __launch_bounds__(MAIN_THREADS, 8) void lds_gather4(const float* __restrict__ x,
                                                               const uint32_t* __restrict__ iwPk,
                                                               const float* __restrict__ bias,
                                                               float* __restrict__ out) {
    __shared__ uint32_t s_x[SLICE_WORDS];   // 32 KB -> 4 blocks/CU, 32 waves/CU
    const int tid = threadIdx.x;
    const int slice  = blockIdx.x >> 2;     // 256 slices
    const int rsplit = blockIdx.x & (N_RSPLIT - 1);
    const int b0  = slice * B_SLICE;
    const int r0g = rsplit * R_PER_BLK;

    { // fused staging: 4 fp32 x-rows -> bf16 pairs. word c*2+p = batches (2p,2p+1)
        const float* xr = x + (size_t)b0 * IN_DIM;
#pragma unroll
        for (int p = 0; p < 2; ++p) {
#pragma unroll
            for (int i = 0; i < 8; ++i) {
                int c = i * MAIN_THREADS + tid;          // coalesced 2KB/wave reads
                float f0 = xr[(size_t)(2 * p)     * IN_DIM + c];
                float f1 = xr[(size_t)(2 * p + 1) * IN_DIM + c];
                s_x[c * 2 + p] = (uint32_t)f2bf(f0) | ((uint32_t)f2bf(f1) << 16);
            }
        }
    }
    __syncthreads();

    const int wv = tid >> 6, lane = tid & 63;

#pragma unroll 1
    for (int pass = 0; pass < 4; ++pass) {
        const int r = r0g + pass * 512 + wv * 64 + lane;   // 64 consecutive r per wave
        float a0 = 0.f, a1 = 0.f, a2 = 0.f, a3 = 0.f;
        const uint32_t* ip = iwPk + r;
#pragma unroll 8
        for (int t = 0; t < NACT; ++t) {
            const uint32_t q = ip[(size_t)t * OUT_DIM];    // 256B/wave packed stream
            const float wg = asf(q & 0xffff0000u);         // bf16 w reinterpret
            uint2 v = *(const uint2*)((const char*)s_x + (q & 0x7ff8u));
            a0 = fmaf(blo(v.x), wg, a0);
            a1 = fmaf(bhi(v.x), wg, a1);
            a2 = fmaf(blo(v.y), wg, a2);
            a3 = fmaf(bhi(v.y), wg, a3);
        }
        const float bv = bias[r];
        const size_t ob = (size_t)b0 * OUT_DIM + r;        // 256B/wave full-line NT stores
        __builtin_nontemporal_store(a0 - bv, &out[ob]);
        __builtin_nontemporal_store(a1 - bv, &out[ob + OUT_DIM]);
        __builtin_nontemporal_store(a2 - bv, &out[ob + 2 * OUT_DIM]);
        __builtin_nontemporal_store(a3 - bv, &out[ob + 3 * OUT_DIM]);
    }
}

// ---- insurance fallback (ws too small): one thread per output ----
__global__ __launch_bounds__(256) void direct_gather(const float* __restrict__ x,
                                                     const int* __restrict__ idx,
                                                     const float* __restrict__ w,
                                                     const float* __restrict__ bias,
                                                     float* __restrict__ out) {
    const uint32_t* gi = (const uint32_t*)idx;
    const bool idx64 = ((gi[1] | gi[3] | gi[5] | gi[7] | gi[9] | gi[11] | gi[13] | gi[15]) == 0u);
    int o = blockIdx.x * 256 + threadIdx.x;
    int b = o >> 13, r = o & (OUT_DIM - 1);
    float acc = 0.f;
    const float* xb = x + (size_t)b * IN_DIM;
    for (int t = 0; t < NACT; ++t) {
        int c = idx64 ? idx[((size_t)r * NACT + t) * 2] : idx[(size_t)r * NACT + t];
        acc = fmaf(xb[c], w[(size_t)r * NACT + t], acc);
    }
    out[(size_t)b * OUT_DIM + r] = acc - bias[r];
}

extern "C" void kernel_launch(void* const* d_in, const int* in_sizes, int n_in,
                              void* d_out, int out_size, void* d_ws, size_t ws_size,
                              hipStream_t stream) {
    const float* x    = (const float*)d_in[0];
    const float* wk   = (const float*)d_in[1];
    const float* bias = (const float*)d_in[2];
    const int*   idx  = (const int*)d_in[3];
    float*       out  = (float*)d_out;

    const size_t iw_bytes = (size_t)NACT * OUT_DIM * 4;   // 1 MB

    if (ws_size >= iw_bytes) {
        uint32_t* iwPk = (uint32_t*)d_ws;
        iw_pack<<<OUT_DIM / 64, 256, 0, stream>>>(idx, wk, iwPk);
        lds_gather4<<<N_SLICE * N_RSPLIT, MAIN_THREADS, 0, stream>>>(x, iwPk, bias, out);
    } else {
        direct_gather<<<(BATCH * OUT_DIM) / 256, 256, 0, stream>>>(x, idx, wk, bias, out);
    }
}

// Round 9
// 36.390 us; speedup vs baseline: 1.5190x; 1.0895x over previous
//
#include <hip/hip_runtime.h>
#include <stdint.h>

// y[b,r] = sum_t x[b, idx[r,t]] * w[r,t] - bias[r]
// fp32 x (1024x4096), fp32 w (8192x32), fp32 bias (8192), int idx (8192x32), fp32 out
//
// r9: LDS-gather (r6) + 32KB slices (r8) + two new levers:
//  - iwPk tile-major [r/64][t][64]: wave reads q via base+imm-offset (t*256B),
//    killing the per-t address-add chain; still 256B/wave coalesced.
//  - float2 accumulators + elementwise_fma -> v_pk_fma_f32 (halves FMA issue).

#define IN_DIM   4096
#define OUT_DIM  8192
#define BATCH    1024
#define NACT     32

#define B_SLICE      4                         // batches per LDS slice
#define N_SLICE      (BATCH / B_SLICE)         // 256
#define SLICE_WORDS  (IN_DIM * 2)              // 8192 u32 = 32 KB
#define R_PER_BLK    2048
#define N_RSPLIT     (OUT_DIM / R_PER_BLK)     // 4
#define MAIN_THREADS 512

typedef float f2v __attribute__((ext_vector_type(2)));

__device__ __forceinline__ ushort f2bf(float f) {
    union { float f; uint32_t i; } v; v.f = f;
    uint32_t b = v.i + 0x7fffu + ((v.i >> 16) & 1u);   // RNE
    return (ushort)(b >> 16);
}
__device__ __forceinline__ float blo(uint32_t v) {
    union { uint32_t i; float f; } u; u.i = v << 16; return u.f;
}
__device__ __forceinline__ float bhi(uint32_t v) {
    union { uint32_t i; float f; } u; u.i = v & 0xffff0000u; return u.f;
}
__device__ __forceinline__ float asf(uint32_t v) {
    union { uint32_t i; float f; } u; u.i = v; return u.f;
}

// ---- idx/w -> iwPk tile-major: iwPk[(r/64)*2048 + t*64 + (r%64)] ----
// entry = (c<<3) | (bf16(w)<<16); unpack = 1 v_and each.
__global__ __launch_bounds__(256) void iw_pack(const int* __restrict__ idx,
                                               const float* __restrict__ w,
                                               uint32_t* __restrict__ iwPk) {
    __shared__ uint32_t sq[64][33];
    const int tid = threadIdx.x;
    const int r0 = blockIdx.x * 64;
    const uint32_t* gi = (const uint32_t*)idx;
    const bool idx64 = ((gi[1] | gi[3] | gi[5] | gi[7] | gi[9] | gi[11] | gi[13] | gi[15]) == 0u);
#pragma unroll
    for (int k = 0; k < 8; ++k) {
        int lin = k * 256 + tid;            // 2048 = 64 rows x 32 t
        int row = lin >> 5, t = lin & 31;
        int c;
        if (!idx64) c = idx[(size_t)(r0 + row) * NACT + t];
        else        c = idx[((size_t)(r0 + row) * NACT + t) * 2];
        float wv = w[(size_t)(r0 + row) * NACT + t];
        sq[row][t] = ((uint32_t)c << 3) | ((uint32_t)f2bf(wv) << 16);
    }
    __syncthreads();
#pragma unroll
    for (int k = 0; k < 8; ++k) {
        int lin = k * 256 + tid;            // t = lin>>6, row = lin&63
        iwPk[(size_t)blockIdx.x * 2048 + lin] = sq[lin & 63][lin >> 6];
    }
}

// ---- main: block = 4-batch slice (32 KB LDS) x 2048 rows; gathers via LDS ----
__global__ __launch_bounds__(MAIN_THREADS, 8) void lds_gather4(const float* __restrict__ x,
                                                               const uint32_t* __restrict__ iwPk,
                                                               const float* __restrict__ bias,
                                                               float* __restrict__ out) {
    __shared__ uint32_t s_x[SLICE_WORDS];   // 32 KB -> 4 blocks/CU, 32 waves/CU
    const int tid = threadIdx.x;
    const int slice  = blockIdx.x >> 2;     // 256 slices
    const int rsplit = blockIdx.x & (N_RSPLIT - 1);
    const int b0  = slice * B_SLICE;
    const int r0g = rsplit * R_PER_BLK;

    { // fused staging: 4 fp32 x-rows -> bf16 pairs. word c*2+p = batches (2p,2p+1)
        const float* xr = x + (size_t)b0 * IN_DIM;
#pragma unroll
        for (int p = 0; p < 2; ++p) {
#pragma unroll
            for (int i = 0; i < 8; ++i) {
                int c = i * MAIN_THREADS + tid;          // coalesced 2KB/wave reads
                float f0 = xr[(size_t)(2 * p)     * IN_DIM + c];
                float f1 = xr[(size_t)(2 * p + 1) * IN_DIM + c];
                s_x[c * 2 + p] = (uint32_t)f2bf(f0) | ((uint32_t)f2bf(f1) << 16);
            }
        }
    }
    __syncthreads();

    const int wv = tid >> 6, lane = tid & 63;

#pragma unroll 1
    for (int pass = 0; pass < 4; ++pass) {
        const int r = r0g + pass * 512 + wv * 64 + lane;   // 64 consecutive r per wave
        // tile-major q base: all 32 t-loads are base + t*256B immediate offsets
        const uint32_t* qb = iwPk + (size_t)(r >> 6) * 2048 + lane;
        f2v a01 = {0.f, 0.f}, a23 = {0.f, 0.f};
#pragma unroll 8
        for (int t = 0; t < NACT; ++t) {
            const uint32_t q = qb[t * 64];                 // imm-offset, 256B/wave
            const float wg = asf(q & 0xffff0000u);         // bf16 w reinterpret
            const f2v w2 = {wg, wg};
            uint2 v = *(const uint2*)((const char*)s_x + (q & 0x7ff8u));
            f2v x01 = {blo(v.x), bhi(v.x)};
            f2v x23 = {blo(v.y), bhi(v.y)};
            a01 = __builtin_elementwise_fma(x01, w2, a01); // v_pk_fma_f32
            a23 = __builtin_elementwise_fma(x23, w2, a23);
        }
        const float bv = bias[r];
        const size_t ob = (size_t)b0 * OUT_DIM + r;        // 256B/wave full-line NT stores
        __builtin_nontemporal_store(a01.x - bv, &out[ob]);
        __builtin_nontemporal_store(a01.y - bv, &out[ob + OUT_DIM]);
        __builtin_nontemporal_store(a23.x - bv, &out[ob + 2 * OUT_DIM]);
        __builtin_nontemporal_store(a23.y - bv, &out[ob + 3 * OUT_DIM]);
    }
}

// ---- insurance fallback (ws too small): one thread per output ----
__global__ __launch_bounds__(256) void direct_gather(const float* __restrict__ x,
                                                     const int* __restrict__ idx,
                                                     const float* __restrict__ w,
                                                     const float* __restrict__ bias,
                                                     float* __restrict__ out) {
    const uint32_t* gi = (const uint32_t*)idx;
    const bool idx64 = ((gi[1] | gi[3] | gi[5] | gi[7] | gi[9] | gi[11] | gi[13] | gi[15]) == 0u);
    int o = blockIdx.x * 256 + threadIdx.x;
    int b = o >> 13, r = o & (OUT_DIM - 1);
    float acc = 0.f;
    const float* xb = x + (size_t)b * IN_DIM;
    for (int t = 0; t < NACT; ++t) {
        int c = idx64 ? idx[((size_t)r * NACT + t) * 2] : idx[(size_t)r * NACT + t];
        acc = fmaf(xb[c], w[(size_t)r * NACT + t], acc);
    }
    out[(size_t)b * OUT_DIM + r] = acc - bias[r];
}

extern "C" void kernel_launch(void* const* d_in, const int* in_sizes, int n_in,
                              void* d_out, int out_size, void* d_ws, size_t ws_size,
                              hipStream_t stream) {
    const float* x    = (const float*)d_in[0];
    const float* wk   = (const float*)d_in[1];
    const float* bias = (const float*)d_in[2];
    const int*   idx  = (const int*)d_in[3];
    float*       out  = (float*)d_out;

    const size_t iw_bytes = (size_t)NACT * OUT_DIM * 4;   // 1 MB

    if (ws_size >= iw_bytes) {
        uint32_t* iwPk = (uint32_t*)d_ws;
        iw_pack<<<OUT_DIM / 64, 256, 0, stream>>>(idx, wk, iwPk);
        lds_gather4<<<N_SLICE * N_RSPLIT, MAIN_THREADS, 0, stream>>>(x, iwPk, bias, out);
    } else {
        direct_gather<<<(BATCH * OUT_DIM) / 256, 256, 0, stream>>>(x, idx, wk, bias, out);
    }
}

// Round 11
// 35.602 us; speedup vs baseline: 1.5526x; 1.0221x over previous
//
#include <hip/hip_runtime.h>
#include <stdint.h>

// y[b,r] = sum_t x[b, idx[r,t]] * w[r,t] - bias[r]
// fp32 x (1024x4096), fp32 w (8192x32), fp32 bias (8192), int idx (8192x32), fp32 out
//
// r11 = r10 with ext_vector_type pointers for nontemporal builtins (HIP_vector_type
// float4* is rejected by __builtin_nontemporal_load on clang/gfx950).
//  - iwPk layout [r/64][t/4][64][4]: q loaded as dwordx4 (4 t per VMEM issue)
//  - staging via nontemporal f4v loads (8 loads vs 32)

#define IN_DIM   4096
#define OUT_DIM  8192
#define BATCH    1024
#define NACT     32

#define B_SLICE      4                         // batches per LDS slice
#define N_SLICE      (BATCH / B_SLICE)         // 256
#define SLICE_WORDS  (IN_DIM * 2)              // 8192 u32 = 32 KB
#define R_PER_BLK    2048
#define N_RSPLIT     (OUT_DIM / R_PER_BLK)     // 4
#define MAIN_THREADS 512

typedef float    f2v __attribute__((ext_vector_type(2)));
typedef float    f4v __attribute__((ext_vector_type(4)));
typedef uint32_t u4v __attribute__((ext_vector_type(4)));
typedef uint32_t u2v __attribute__((ext_vector_type(2)));

__device__ __forceinline__ ushort f2bf(float f) {
    union { float f; uint32_t i; } v; v.f = f;
    uint32_t b = v.i + 0x7fffu + ((v.i >> 16) & 1u);   // RNE
    return (ushort)(b >> 16);
}
__device__ __forceinline__ float blo(uint32_t v) {
    union { uint32_t i; float f; } u; u.i = v << 16; return u.f;
}
__device__ __forceinline__ float bhi(uint32_t v) {
    union { uint32_t i; float f; } u; u.i = v & 0xffff0000u; return u.f;
}
__device__ __forceinline__ float asf(uint32_t v) {
    union { uint32_t i; float f; } u; u.i = v; return u.f;
}

// ---- idx/w -> iwPk: [rtile=r/64][tg=t/4][rl=r%64][ti=t%4] ----
// entry = (c<<3) | (bf16(w)<<16)
__global__ __launch_bounds__(256) void iw_pack(const int* __restrict__ idx,
                                               const float* __restrict__ w,
                                               uint32_t* __restrict__ iwPk) {
    __shared__ uint32_t sq[64][33];
    const int tid = threadIdx.x;
    const int r0 = blockIdx.x * 64;
    const uint32_t* gi = (const uint32_t*)idx;
    const bool idx64 = ((gi[1] | gi[3] | gi[5] | gi[7] | gi[9] | gi[11] | gi[13] | gi[15]) == 0u);
#pragma unroll
    for (int k = 0; k < 8; ++k) {
        int lin = k * 256 + tid;            // 2048 = 64 rows x 32 t
        int row = lin >> 5, t = lin & 31;
        int c;
        if (!idx64) c = idx[(size_t)(r0 + row) * NACT + t];
        else        c = idx[((size_t)(r0 + row) * NACT + t) * 2];
        float wv = w[(size_t)(r0 + row) * NACT + t];
        sq[row][t] = ((uint32_t)c << 3) | ((uint32_t)f2bf(wv) << 16);
    }
    __syncthreads();
#pragma unroll
    for (int k = 0; k < 8; ++k) {
        int lin = k * 256 + tid;            // lin = tg*256 + rl*4 + ti
        int ti = lin & 3, rl = (lin >> 2) & 63, tg = lin >> 8;
        iwPk[(size_t)blockIdx.x * 2048 + lin] = sq[rl][tg * 4 + ti];
    }
}

// ---- main: block = 4-batch slice (32 KB LDS) x 2048 rows; gathers via LDS ----
__global__ __launch_bounds__(MAIN_THREADS, 8) void lds_gather4(const float* __restrict__ x,
                                                               const uint32_t* __restrict__ iwPk,
                                                               const float* __restrict__ bias,
                                                               float* __restrict__ out) {
    __shared__ uint32_t s_x[SLICE_WORDS];   // 32 KB -> 4 blocks/CU, 32 waves/CU
    const int tid = threadIdx.x;
    const int slice  = blockIdx.x >> 2;     // 256 slices
    const int rsplit = blockIdx.x & (N_RSPLIT - 1);
    const int b0  = slice * B_SLICE;
    const int r0g = rsplit * R_PER_BLK;

    { // staging: 4 fp32 rows via NT f4v; word c*2+p = batches (2p,2p+1)
        const float* xr = x + (size_t)b0 * IN_DIM;
#pragma unroll
        for (int i = 0; i < 2; ++i) {
            int c4 = (i * MAIN_THREADS + tid) * 4;
            f4v r0 = __builtin_nontemporal_load((const f4v*)(xr + c4));
            f4v r1 = __builtin_nontemporal_load((const f4v*)(xr + IN_DIM + c4));
            f4v r2 = __builtin_nontemporal_load((const f4v*)(xr + 2 * IN_DIM + c4));
            f4v r3 = __builtin_nontemporal_load((const f4v*)(xr + 3 * IN_DIM + c4));
            u4v wA, wB;
            wA.x = f2bf(r0.x) | ((uint32_t)f2bf(r1.x) << 16);   // (c4  ,p0)
            wA.y = f2bf(r2.x) | ((uint32_t)f2bf(r3.x) << 16);   // (c4  ,p1)
            wA.z = f2bf(r0.y) | ((uint32_t)f2bf(r1.y) << 16);   // (c4+1,p0)
            wA.w = f2bf(r2.y) | ((uint32_t)f2bf(r3.y) << 16);
            wB.x = f2bf(r0.z) | ((uint32_t)f2bf(r1.z) << 16);
            wB.y = f2bf(r2.z) | ((uint32_t)f2bf(r3.z) << 16);
            wB.z = f2bf(r0.w) | ((uint32_t)f2bf(r1.w) << 16);
            wB.w = f2bf(r2.w) | ((uint32_t)f2bf(r3.w) << 16);
            *(u4v*)&s_x[c4 * 2]     = wA;
            *(u4v*)&s_x[c4 * 2 + 4] = wB;
        }
    }
    __syncthreads();

    const int wv = tid >> 6, lane = tid & 63;

#pragma unroll 1
    for (int pass = 0; pass < 4; ++pass) {
        const int r = r0g + pass * 512 + wv * 64 + lane;   // 64 consecutive r per wave
        const uint32_t* qb = iwPk + (size_t)(r >> 6) * 2048 + (lane << 2);
        f2v a01 = {0.f, 0.f}, a23 = {0.f, 0.f};
#pragma unroll
        for (int tg = 0; tg < 8; ++tg) {
            const u4v qv = *(const u4v*)(qb + tg * 256);   // 4 t per dwordx4, 1KB/wave
#pragma unroll
            for (int ti = 0; ti < 4; ++ti) {
                const uint32_t q = qv[ti];
                const float wg = asf(q & 0xffff0000u);     // bf16 w reinterpret
                const f2v w2 = {wg, wg};
                u2v v = *(const u2v*)((const char*)s_x + (q & 0x7ff8u));
                f2v x01 = {blo(v.x), bhi(v.x)};
                f2v x23 = {blo(v.y), bhi(v.y)};
                a01 = __builtin_elementwise_fma(x01, w2, a01); // v_pk_fma_f32
                a23 = __builtin_elementwise_fma(x23, w2, a23);
            }
        }
        const float bv = bias[r];
        const size_t ob = (size_t)b0 * OUT_DIM + r;        // 256B/wave full-line NT stores
        __builtin_nontemporal_store(a01.x - bv, &out[ob]);
        __builtin_nontemporal_store(a01.y - bv, &out[ob + OUT_DIM]);
        __builtin_nontemporal_store(a23.x - bv, &out[ob + 2 * OUT_DIM]);
        __builtin_nontemporal_store(a23.y - bv, &out[ob + 3 * OUT_DIM]);
    }
}

// ---- insurance fallback (ws too small): one thread per output ----
__global__ __launch_bounds__(256) void direct_gather(const float* __restrict__ x,
                                                     const int* __restrict__ idx,
                                                     const float* __restrict__ w,
                                                     const float* __restrict__ bias,
                                                     float* __restrict__ out) {
    const uint32_t* gi = (const uint32_t*)idx;
    const bool idx64 = ((gi[1] | gi[3] | gi[5] | gi[7] | gi[9] | gi[11] | gi[13] | gi[15]) == 0u);
    int o = blockIdx.x * 256 + threadIdx.x;
    int b = o >> 13, r = o & (OUT_DIM - 1);
    float acc = 0.f;
    const float* xb = x + (size_t)b * IN_DIM;
    for (int t = 0; t < NACT; ++t) {
        int c = idx64 ? idx[((size_t)r * NACT + t) * 2] : idx[(size_t)r * NACT + t];
        acc = fmaf(xb[c], w[(size_t)r * NACT + t], acc);
    }
    out[(size_t)b * OUT_DIM + r] = acc - bias[r];
}

extern "C" void kernel_launch(void* const* d_in, const int* in_sizes, int n_in,
                              void* d_out, int out_size, void* d_ws, size_t ws_size,
                              hipStream_t stream) {
    const float* x    = (const float*)d_in[0];
    const float* wk   = (const float*)d_in[1];
    const float* bias = (const float*)d_in[2];
    const int*   idx  = (const int*)d_in[3];
    float*       out  = (float*)d_out;

    const size_t iw_bytes = (size_t)NACT * OUT_DIM * 4;   // 1 MB

    if (ws_size >= iw_bytes) {
        uint32_t* iwPk = (uint32_t*)d_ws;
        iw_pack<<<OUT_DIM / 64, 256, 0, stream>>>(idx, wk, iwPk);
        lds_gather4<<<N_SLICE * N_RSPLIT, MAIN_THREADS, 0, stream>>>(x, iwPk, bias, out);
    } else {
        direct_gather<<<(BATCH * OUT_DIM) / 256, 256, 0, stream>>>(x, idx, wk, bias, out);
    }
}